// Round 7
// baseline (352.314 us; speedup 1.0000x reference)
//
#include <hip/hip_runtime.h>

// AxisAttention: x(8,256,128,128) -> per (b,w) sequence over h: QKV GEMM, 4-head
// attention (S=128, d=64), proj GEMM, transposed fp32 output.
// All matmuls: v_mfma_f32_16x16x32_f16, fp32 accum.
// A/B frag: lane l -> row/col (l&15), k read with identical expression on A and B.
// D frag:   col=l&15, row=4*(l>>4)+r [m89-verified].
// v7: prep_x transposes x -> xt[b-local][t=(h,w)][c] fp16 ONCE (aliases attnout,
//     zero extra ws); k1 becomes a clean 128fx256t GEMM with pure u4 staging.

typedef _Float16 h4 __attribute__((ext_vector_type(4)));
typedef _Float16 h8 __attribute__((ext_vector_type(8)));
typedef float f4 __attribute__((ext_vector_type(4)));
typedef unsigned int u4 __attribute__((ext_vector_type(4)));

#define MFMA32(a, b, c) __builtin_amdgcn_mfma_f32_16x16x32_f16((a), (b), (c), 0, 0, 0)

// ---------------- prep: W^T fp16 (wqt[f][c], wpt[f][c]) ----------------
__global__ __launch_bounds__(256) void prep_w(const float* __restrict__ Wqkv,
                                              const float* __restrict__ Wproj,
                                              _Float16* __restrict__ wqt,
                                              _Float16* __restrict__ wpt) {
  int i = blockIdx.x * 256 + threadIdx.x;  // 196608 + 65536
  if (i < 768 * 256) {
    int f = i >> 8, c = i & 255;
    wqt[i] = (_Float16)Wqkv[c * 768 + f];
  } else {
    int j = i - 768 * 256;
    int f = j >> 8, c = j & 255;
    wpt[j] = (_Float16)Wproj[c * 256 + f];
  }
}

// ---------------- prep_x: x[b][c][h][w] fp32 -> xt[bl][h*128+w][c] fp16 --------
// grid (h=128, bl=nbv), block 256. LDS tile [256 c][136 pitch].
__global__ __launch_bounds__(256) void prep_x(const float* __restrict__ x,
                                              _Float16* __restrict__ xt,
                                              int b_base) {
  const int h = blockIdx.x, bl = blockIdx.y;
  const int b = b_base + bl;
  const int tid = threadIdx.x;
  __shared__ __align__(16) _Float16 sT[256 * 136];  // 69632 B

  // phase 1: coalesced f4 reads along w, h4 LDS writes [c][w]
  const int wj = tid & 31, cg = tid >> 5;  // wj: f4-chunk of w; cg: c-group
#pragma unroll
  for (int ci = 0; ci < 32; ++ci) {
    const int c = cg * 32 + ci;
    f4 v = *(const f4*)(x + (((long)b * 256 + c) * 128 + h) * 128 + wj * 4);
    h4 o;
    o[0] = (_Float16)v[0]; o[1] = (_Float16)v[1];
    o[2] = (_Float16)v[2]; o[3] = (_Float16)v[3];
    *(h4*)(sT + c * 136 + wj * 4) = o;
  }
  __syncthreads();

  // phase 2: gather columns (scalar LDS reads, 2-way banks), h8 global writes
  const int w = tid & 127, ch = (tid >> 7) * 128;
  _Float16* dst = xt + (((long)bl * 128 + h) * 128 + w) * 256 + ch;
#pragma unroll
  for (int cc = 0; cc < 16; ++cc) {
    h8 hv;
#pragma unroll
    for (int i = 0; i < 8; ++i) hv[i] = sT[(ch + cc * 8 + i) * 136 + w];
    *(h8*)(dst + cc * 8) = hv;
  }
}

// ---------------- K1: qkv[f][t] = Wqkv^T[f][c] * xt[t][c] + bqkv ----------------
// 1D grid 384*nbv, XCD-swizzled (6 ft-blocks sharing a B tile -> same XCD).
// Tile 128 f x 256 t, K=256, 4 waves (2f x 2t), pure u4 staging.
// qkv layout: [qi*nb+bl][head][w][h*64+d]  (16KB contiguous per (head,w))
__global__ __launch_bounds__(256) void k1_qkv(const _Float16* __restrict__ xt,
                                              const _Float16* __restrict__ wqt,
                                              const float* __restrict__ bqkv,
                                              _Float16* __restrict__ qkv,
                                              int nb) {
  const int wg = blockIdx.x;
  const int xcd = wg & 7, gseq = wg >> 3;
  const int ft = gseq % 6, ghi = gseq / 6;
  const int G = ghi * 8 + xcd;          // [0, 64*nbv)
  const int tt = G & 63, bl = G >> 6;

  const int tid = threadIdx.x;
  const int lane = tid & 63, wv = tid >> 6;
  const int g = lane >> 4, l16 = lane & 15;
  const int wr = wv >> 1, wc = wv & 1;  // wave -> (f-half, t-half)
  const int f0 = ft * 128;

  __shared__ __align__(16) char smem[(128 + 256) * 72 * 2];  // 55296 B
  _Float16* sA = (_Float16*)smem;       // [128 f][72]
  _Float16* sB = sA + 128 * 72;         // [256 t][72]
  _Float16* sO = sA;                    // reuse: [256 t][72]

  f4 acc[4][8];
#pragma unroll
  for (int mt = 0; mt < 4; ++mt)
#pragma unroll
    for (int nt = 0; nt < 8; ++nt)
#pragma unroll
      for (int r = 0; r < 4; ++r) acc[mt][nt][r] = 0.f;

  const _Float16* Bb = xt + ((long)bl * 16384 + tt * 256) * 256;

  for (int kc = 0; kc < 4; ++kc) {
    const int c0 = kc * 64;
    // stage A: 128 rows x 8 u4
#pragma unroll
    for (int i = 0; i < 4; ++i) {
      int u = tid + 256 * i;
      int row = u >> 3, cc = u & 7;
      *(u4*)(sA + row * 72 + cc * 8) =
          *(const u4*)(wqt + (long)(f0 + row) * 256 + c0 + cc * 8);
    }
    // stage B: 256 rows x 8 u4
#pragma unroll
    for (int i = 0; i < 8; ++i) {
      int u = tid + 256 * i;
      int row = u >> 3, cc = u & 7;
      *(u4*)(sB + row * 72 + cc * 8) =
          *(const u4*)(Bb + (long)row * 256 + c0 + cc * 8);
    }
    __syncthreads();
#pragma unroll
    for (int ks = 0; ks < 2; ++ks) {
      const int k = ks * 32 + 8 * g;
      h8 af[4], bf[8];
#pragma unroll
      for (int mt = 0; mt < 4; ++mt)
        af[mt] = *(const h8*)(sA + (wr * 64 + mt * 16 + l16) * 72 + k);
#pragma unroll
      for (int nt = 0; nt < 8; ++nt)
        bf[nt] = *(const h8*)(sB + (wc * 128 + nt * 16 + l16) * 72 + k);
#pragma unroll
      for (int mt = 0; mt < 4; ++mt)
#pragma unroll
        for (int nt = 0; nt < 8; ++nt)
          acc[mt][nt] = MFMA32(af[mt], bf[nt], acc[mt][nt]);
    }
    __syncthreads();
  }

  // epilogue: two f-half rounds; repack via sO[256 t][72], store 128B runs
#pragma unroll
  for (int h2 = 0; h2 < 2; ++h2) {
    if (h2) __syncthreads();
    if (wr == h2) {
#pragma unroll
      for (int mt = 0; mt < 4; ++mt) {
        f4 bb = *(const f4*)(bqkv + f0 + h2 * 64 + mt * 16 + 4 * g);
#pragma unroll
        for (int nt = 0; nt < 8; ++nt) {
          const int tl = wc * 128 + nt * 16 + l16;
#pragma unroll
          for (int r = 0; r < 4; ++r)
            sO[tl * 72 + mt * 16 + 4 * g + r] = (_Float16)(acc[mt][nt][r] + bb[r]);
        }
      }
    }
    __syncthreads();
    const int fh = f0 + h2 * 64;
    const int qi = fh >> 8, head = (fh >> 6) & 3;
    const int tg = tt * 256 + tid;
    const int hI = tg >> 7, w = tg & 127;
    _Float16* dst =
        qkv + (((long)(qi * nb + bl) * 4 + head) * 128 + w) * 8192 + hI * 64;
#pragma unroll
    for (int e = 0; e < 8; ++e)
      *(u4*)(dst + e * 8) = *(const u4*)(sO + tid * 72 + e * 8);
  }
}

// ---------------- K2: attention per (w, head, bl) ----------------
__global__ __launch_bounds__(256) void k2_attn(const _Float16* __restrict__ qkv,
                                               _Float16* __restrict__ attnout,
                                               int nb) {
  const int w = blockIdx.x, head = blockIdx.y, bl = blockIdx.z;
  const int tid = threadIdx.x;
  const int lane = tid & 63, wv = tid >> 6;
  const int g = lane >> 4, l16 = lane & 15;

  __shared__ __align__(16) char smem[(128 * 72 * 2 + 64 * 136) * 2];  // 54272 B
  _Float16* sQ = (_Float16*)smem;       // [128 h][72]
  _Float16* sK = sQ + 128 * 72;         // [128 h][72]
  _Float16* sVT = sK + 128 * 72;        // [64 d][136]
  _Float16* sP = sQ;                    // reuse: [128 hq][136]
  _Float16* sO = sQ;                    // reuse: [128 h][72]

  const long base = (((long)bl * 4 + head) * 128 + w) * 8192;
  const long QS = (long)nb * 4 * 128 * 8192;  // qi stride
  const _Float16* qg = qkv + base;
  const _Float16* kg = qkv + base + QS;
  const _Float16* vg = qkv + base + 2 * QS;

  // stage Q, K row-major [h][d]: 128 rows x 8 u4-chunks
#pragma unroll
  for (int i = 0; i < 4; ++i) {
    int u = tid + 256 * i;
    int hh = u >> 3, dq = u & 7;
    *(u4*)(sQ + hh * 72 + dq * 8) = *(const u4*)(qg + hh * 64 + dq * 8);
    *(u4*)(sK + hh * 72 + dq * 8) = *(const u4*)(kg + hh * 64 + dq * 8);
  }
  // stage V transposed -> sVT[d][h]
  {
    const int hh = tid & 127, dc = tid >> 7;
#pragma unroll
    for (int jj = 0; jj < 4; ++jj) {
      u4 vv = *(const u4*)(vg + hh * 64 + dc * 32 + jj * 8);
      const _Float16* pe = (const _Float16*)&vv;
#pragma unroll
      for (int e = 0; e < 8; ++e)
        sVT[(dc * 32 + jj * 8 + e) * 136 + hh] = pe[e];
    }
  }
  __syncthreads();

  // S^T[hk][hq], per wave: hq in [wv*32, wv*32+32)
  f4 accS[8][2];
  for (int i = 0; i < 8; ++i)
    for (int jt = 0; jt < 2; ++jt)
      for (int r = 0; r < 4; ++r) accS[i][jt][r] = 0.f;
#pragma unroll
  for (int ks = 0; ks < 2; ++ks) {
    const int k = ks * 32 + 8 * g;
    h8 af[8], bf[2];
#pragma unroll
    for (int i = 0; i < 8; ++i)
      af[i] = *(const h8*)(sK + (i * 16 + l16) * 72 + k);
#pragma unroll
    for (int jt = 0; jt < 2; ++jt)
      bf[jt] = *(const h8*)(sQ + (wv * 32 + jt * 16 + l16) * 72 + k);
#pragma unroll
    for (int i = 0; i < 8; ++i)
#pragma unroll
      for (int jt = 0; jt < 2; ++jt)
        accS[i][jt] = MFMA32(af[i], bf[jt], accS[i][jt]);
  }

  // softmax over hk (per-lane column + shfl 16/32)
  float rinv[2];
#pragma unroll
  for (int jt = 0; jt < 2; ++jt) {
    float m = -1e30f;
    for (int i = 0; i < 8; ++i)
      for (int r = 0; r < 4; ++r) m = fmaxf(m, accS[i][jt][r]);
    m = fmaxf(m, __shfl_xor(m, 16));
    m = fmaxf(m, __shfl_xor(m, 32));
    float s = 0.f;
    for (int i = 0; i < 8; ++i)
      for (int r = 0; r < 4; ++r) {
        float p = __expf((accS[i][jt][r] - m) * 0.125f);
        accS[i][jt][r] = p;
        s += p;
      }
    s += __shfl_xor(s, 16);
    s += __shfl_xor(s, 32);
    rinv[jt] = 1.0f / s;
  }

  __syncthreads();  // done reading sQ/sK
  // write P (unnormalized) to sP[hq][hk] via verified D layout
#pragma unroll
  for (int jt = 0; jt < 2; ++jt) {
    const int hq = wv * 32 + jt * 16 + l16;
#pragma unroll
    for (int i = 0; i < 8; ++i) {
      h4 pv;
      pv[0] = (_Float16)accS[i][jt][0];
      pv[1] = (_Float16)accS[i][jt][1];
      pv[2] = (_Float16)accS[i][jt][2];
      pv[3] = (_Float16)accS[i][jt][3];
      *(h4*)(sP + hq * 136 + i * 16 + 4 * g) = pv;
    }
  }
  __syncthreads();

  // O^T[d][hq] = V^T * P^T, K = 128
  f4 accO[4][2];
  for (int mt = 0; mt < 4; ++mt)
    for (int jt = 0; jt < 2; ++jt)
      for (int r = 0; r < 4; ++r) accO[mt][jt][r] = 0.f;
#pragma unroll
  for (int i2 = 0; i2 < 4; ++i2) {
    const int k = i2 * 32 + 8 * g;
    h8 av[4], pb[2];
#pragma unroll
    for (int mt = 0; mt < 4; ++mt)
      av[mt] = *(const h8*)(sVT + (mt * 16 + l16) * 136 + k);
#pragma unroll
    for (int jt = 0; jt < 2; ++jt)
      pb[jt] = *(const h8*)(sP + (wv * 32 + jt * 16 + l16) * 136 + k);
#pragma unroll
    for (int mt = 0; mt < 4; ++mt)
#pragma unroll
      for (int jt = 0; jt < 2; ++jt)
        accO[mt][jt] = MFMA32(av[mt], pb[jt], accO[mt][jt]);
  }

  __syncthreads();  // done reading sP
  // normalize + repack to sO[h][d] (pitch 72)
#pragma unroll
  for (int mt = 0; mt < 4; ++mt)
#pragma unroll
    for (int jt = 0; jt < 2; ++jt)
#pragma unroll
      for (int r = 0; r < 4; ++r)
        sO[(wv * 32 + jt * 16 + l16) * 72 + mt * 16 + 4 * g + r] =
            (_Float16)(accO[mt][jt][r] * rinv[jt]);
  __syncthreads();

  // store attnout[bl][(h*128 + w)][head*64 + d] as u4s
  const int hh = tid >> 1, d0 = (tid & 1) * 32;
  const _Float16* s = sO + hh * 72 + d0;
  _Float16* dst = attnout + ((long)bl * 16384 + hh * 128 + w) * 256 + head * 64 + d0;
#pragma unroll
  for (int e = 0; e < 4; ++e)
    *(u4*)(dst + e * 8) = *(const u4*)(s + e * 8);
}

// ---------------- K3: out[b][co][t] = Wproj^T[co][c]*attnout[t][c]+bproj --------
__global__ __launch_bounds__(256) void k3_proj(const _Float16* __restrict__ attnout,
                                               const _Float16* __restrict__ wpt,
                                               const float* __restrict__ bproj,
                                               float* __restrict__ out,
                                               int b_base, int nb) {
  const int ct = blockIdx.x, tt = blockIdx.y, bl = blockIdx.z;
  const int b = b_base + bl;
  const int tid = threadIdx.x;
  const int lane = tid & 63, wv = tid >> 6;
  const int g = lane >> 4, l16 = lane & 15;
  const int co0 = ct * 128;
  const long t0 = (long)tt * 128;

  __shared__ __align__(16) char smem[128 * 72 * 2 * 2];  // 36864 B
  _Float16* sA = (_Float16*)smem;     // [128 co][72]
  _Float16* sB = sA + 128 * 72;       // [128 t][72]
  float* sOut = (float*)smem;         // reuse: [64][132] f32

  f4 acc[8][2];
  for (int mt = 0; mt < 8; ++mt)
    for (int nt = 0; nt < 2; ++nt)
      for (int r = 0; r < 4; ++r) acc[mt][nt][r] = 0.f;

  const _Float16* Bb = attnout + ((long)bl * 16384 + t0) * 256;

  for (int kc = 0; kc < 4; ++kc) {
    const int c0 = kc * 64;
#pragma unroll
    for (int i = 0; i < 4; ++i) {
      int u = tid + 256 * i;
      int row = u >> 3, cc = u & 7;
      *(u4*)(sA + row * 72 + cc * 8) =
          *(const u4*)(wpt + (long)(co0 + row) * 256 + c0 + cc * 8);
      *(u4*)(sB + row * 72 + cc * 8) = *(const u4*)(Bb + (long)row * 256 + c0 + cc * 8);
    }
    __syncthreads();
#pragma unroll
    for (int ks = 0; ks < 2; ++ks) {
      const int k = ks * 32 + 8 * g;
      h8 af[8], bf[2];
#pragma unroll
      for (int mt = 0; mt < 8; ++mt)
        af[mt] = *(const h8*)(sA + (mt * 16 + l16) * 72 + k);
#pragma unroll
      for (int nt = 0; nt < 2; ++nt)
        bf[nt] = *(const h8*)(sB + (wv * 32 + nt * 16 + l16) * 72 + k);
#pragma unroll
      for (int mt = 0; mt < 8; ++mt)
#pragma unroll
        for (int nt = 0; nt < 2; ++nt)
          acc[mt][nt] = MFMA32(af[mt], bf[nt], acc[mt][nt]);
    }
    __syncthreads();
  }

  // epilogue: repack halves through LDS, write 512B-contiguous fp32 rows
#pragma unroll
  for (int half = 0; half < 2; ++half) {
    if (half) __syncthreads();
#pragma unroll
    for (int mt2 = 0; mt2 < 4; ++mt2) {
      const int mt = half * 4 + mt2;
      f4 bb = *(const f4*)(bproj + co0 + mt * 16 + 4 * g);
#pragma unroll
      for (int nt = 0; nt < 2; ++nt)
#pragma unroll
        for (int r = 0; r < 4; ++r)
          sOut[(mt2 * 16 + 4 * g + r) * 132 + wv * 32 + nt * 16 + l16] =
              acc[mt][nt][r] + bb[r];
    }
    __syncthreads();
    const int row = tid >> 2, seg = (tid & 3) * 32;
    const float* s = sOut + row * 132 + seg;
    float* dst = out + ((long)b * 256 + co0 + half * 64 + row) * 16384 + t0 + seg;
#pragma unroll
    for (int e = 0; e < 8; ++e)
      *(f4*)(dst + e * 4) = *(const f4*)(s + e * 4);
  }
}

// ---------------- launch ----------------
extern "C" void kernel_launch(void* const* d_in, const int* in_sizes, int n_in,
                              void* d_out, int out_size, void* d_ws, size_t ws_size,
                              hipStream_t stream) {
  const float* x = (const float*)d_in[0];
  const float* Wqkv = (const float*)d_in[1];
  const float* bqkv = (const float*)d_in[2];
  const float* Wproj = (const float*)d_in[3];
  const float* bproj = (const float*)d_in[4];
  float* out = (float*)d_out;

  char* ws = (char*)d_ws;
  // Layout: [wqt 384K][wpt 128K][qkv nb*24Mi][shared nb*8Mi (xt, then attnout)]
  const long WQT = 393216L, WPT = 131072L;
  const long PER_B = 25165824L + 8388608L;  // 24Mi qkv + 8Mi shared
  long nb_l = ((long)ws_size - (WQT + WPT)) / PER_B;
  int nb = nb_l < 1 ? 1 : (nb_l > 8 ? 8 : (int)nb_l);

  _Float16* wqt = (_Float16*)ws;
  _Float16* wpt = (_Float16*)(ws + WQT);
  _Float16* qkv = (_Float16*)(ws + WQT + WPT);
  _Float16* shared = (_Float16*)(ws + WQT + WPT + (long)nb * 25165824L);
  _Float16* xt = shared;       // live: prep_x -> k1
  _Float16* attnout = shared;  // live: k2 -> k3 (after xt dead)

  prep_w<<<1024, 256, 0, stream>>>(Wqkv, Wproj, wqt, wpt);

  for (int b0 = 0; b0 < 8; b0 += nb) {
    int nbv = (8 - b0 < nb) ? (8 - b0) : nb;
    prep_x<<<dim3(128, nbv), 256, 0, stream>>>(x, xt, b0);
    k1_qkv<<<384 * nbv, 256, 0, stream>>>(xt, wqt, bqkv, qkv, nbv);
    k2_attn<<<dim3(128, 4, nbv), 256, 0, stream>>>(qkv, attnout, nbv);
    k3_proj<<<dim3(2, 128, nbv), 256, 0, stream>>>(attnout, wpt, bproj, out, b0, nbv);
  }
}

// Round 8
// 266.808 us; speedup vs baseline: 1.3205x; 1.3205x over previous
//
#include <hip/hip_runtime.h>

// AxisAttention: x(8,256,128,128) -> per (b,w) sequence over h: QKV GEMM, 4-head
// attention (S=128, d=64), proj GEMM, transposed fp32 output.
// All matmuls: v_mfma_f32_16x16x32_f16, fp32 accum.
// v8: k1/k3 in m97 structure: global_load_lds width-16 staging, 128x128 tile,
//     BK=64, 2x2 waves, acc[4][4], LDS 33KB -> 4 blocks/CU, launch_bounds(256,4).

typedef _Float16 h4 __attribute__((ext_vector_type(4)));
typedef _Float16 h8 __attribute__((ext_vector_type(8)));
typedef float f4 __attribute__((ext_vector_type(4)));
typedef unsigned int u2 __attribute__((ext_vector_type(2)));
typedef unsigned int u4 __attribute__((ext_vector_type(4)));

#define MFMA32(a, b, c) __builtin_amdgcn_mfma_f32_16x16x32_f16((a), (b), (c), 0, 0, 0)

__device__ __forceinline__ void gll16(const _Float16* g, _Float16* l) {
  __builtin_amdgcn_global_load_lds(
      (const __attribute__((address_space(1))) void*)g,
      (__attribute__((address_space(3))) void*)l, 16, 0, 0);
}

// ---------------- prep: W^T fp16 (wqt[f][c], wpt[f][c]) ----------------
__global__ __launch_bounds__(256) void prep_w(const float* __restrict__ Wqkv,
                                              const float* __restrict__ Wproj,
                                              _Float16* __restrict__ wqt,
                                              _Float16* __restrict__ wpt) {
  int i = blockIdx.x * 256 + threadIdx.x;  // 196608 + 65536
  if (i < 768 * 256) {
    int f = i >> 8, c = i & 255;
    wqt[i] = (_Float16)Wqkv[c * 768 + f];
  } else {
    int j = i - 768 * 256;
    int f = j >> 8, c = j & 255;
    wpt[j] = (_Float16)Wproj[c * 256 + f];
  }
}

// ---------------- prep_x: x[b][c][h][w] fp32 -> xt[bl][h*128+w][c] fp16 --------
__global__ __launch_bounds__(256) void prep_x(const float* __restrict__ x,
                                              _Float16* __restrict__ xt,
                                              int b_base) {
  const int h = blockIdx.x, bl = blockIdx.y;
  const int b = b_base + bl;
  const int tid = threadIdx.x;
  __shared__ __align__(16) _Float16 sT[256 * 136];  // 69632 B

  const int wj = tid & 31, cg = tid >> 5;
#pragma unroll
  for (int ci = 0; ci < 32; ++ci) {
    const int c = cg * 32 + ci;
    f4 v = *(const f4*)(x + (((long)b * 256 + c) * 128 + h) * 128 + wj * 4);
    h4 o;
    o[0] = (_Float16)v[0]; o[1] = (_Float16)v[1];
    o[2] = (_Float16)v[2]; o[3] = (_Float16)v[3];
    *(h4*)(sT + c * 136 + wj * 4) = o;
  }
  __syncthreads();

  const int w = tid & 127, ch = (tid >> 7) * 128;
  _Float16* dst = xt + (((long)bl * 128 + h) * 128 + w) * 256 + ch;
#pragma unroll
  for (int cc = 0; cc < 16; ++cc) {
    h8 hv;
#pragma unroll
    for (int i = 0; i < 8; ++i) hv[i] = sT[(ch + cc * 8 + i) * 136 + w];
    *(h8*)(dst + cc * 8) = hv;
  }
}

// ---------------- K1: qkv[f][t] = Wqkv^T[f][c] * xt[t][c] + bqkv ----------------
// 1D grid 768*nbv XCD-swizzled. Tile 128f x 128t, BK=64, 4 waves (2f x 2t).
// Staging via global_load_lds width-16 into linear [128][64] LDS tiles.
// qkv layout: [qi*nb+bl][head][w][h*64+d]
__global__ __launch_bounds__(256, 4) void k1_qkv(const _Float16* __restrict__ xt,
                                                 const _Float16* __restrict__ wqt,
                                                 const float* __restrict__ bqkv,
                                                 _Float16* __restrict__ qkv,
                                                 int nb) {
  const int wg = blockIdx.x;
  const int xcd = wg & 7, gseq = wg >> 3;
  const int ft = gseq % 6, ghi = gseq / 6;
  const int G = ghi * 8 + xcd;          // [0, 128*nbv)
  const int tt = G & 127, bl = G >> 7;  // tile: h=tt fixed, w=0..127

  const int tid = threadIdx.x;
  const int lane = tid & 63, wv = tid >> 6;
  const int g = lane >> 4, l16 = lane & 15;
  const int wr = wv >> 1, wc = wv & 1;
  const int f0 = ft * 128;

  __shared__ __align__(16) char smem[33792];
  _Float16* sA = (_Float16*)smem;   // [128 f][64]
  _Float16* sB = sA + 128 * 64;     // [128 t][64]
  _Float16* sO = sA;                // reuse: [128 w][132]

  f4 acc[4][4];
#pragma unroll
  for (int mt = 0; mt < 4; ++mt)
#pragma unroll
    for (int nt = 0; nt < 4; ++nt)
#pragma unroll
      for (int r = 0; r < 4; ++r) acc[mt][nt][r] = 0.f;

  const _Float16* Ab = wqt + (long)f0 * 256;
  const _Float16* Bb = xt + ((long)bl * 16384 + tt * 128) * 256;
  const int r0 = wv * 32;                       // wave's 32-row stripe
  const int rl = lane >> 3, ch = (lane & 7) * 8;  // per-lane row/chunk in stripe

  for (int kc = 0; kc < 4; ++kc) {
    const int c0 = kc * 64;
#pragma unroll
    for (int i = 0; i < 4; ++i) {
      const int row = r0 + i * 8 + rl;
      gll16(Ab + (long)row * 256 + c0 + ch, sA + (r0 + i * 8) * 64);
      gll16(Bb + (long)row * 256 + c0 + ch, sB + (r0 + i * 8) * 64);
    }
    __syncthreads();
#pragma unroll
    for (int ks = 0; ks < 2; ++ks) {
      const int k = ks * 32 + 8 * g;
      h8 af[4], bf[4];
#pragma unroll
      for (int mt = 0; mt < 4; ++mt)
        af[mt] = *(const h8*)(sA + (wr * 64 + mt * 16 + l16) * 64 + k);
#pragma unroll
      for (int nt = 0; nt < 4; ++nt)
        bf[nt] = *(const h8*)(sB + (wc * 64 + nt * 16 + l16) * 64 + k);
#pragma unroll
      for (int mt = 0; mt < 4; ++mt)
#pragma unroll
        for (int nt = 0; nt < 4; ++nt)
          acc[mt][nt] = MFMA32(af[mt], bf[nt], acc[mt][nt]);
    }
    __syncthreads();
  }

  // bias + repack into sO[w][f_local] (pitch 132, 8B-aligned h4 rows)
#pragma unroll
  for (int mt = 0; mt < 4; ++mt) {
    f4 bb = *(const f4*)(bqkv + f0 + wr * 64 + mt * 16 + 4 * g);
#pragma unroll
    for (int nt = 0; nt < 4; ++nt) {
      const int wl = wc * 64 + nt * 16 + l16;
#pragma unroll
      for (int r = 0; r < 4; ++r)
        sO[wl * 132 + wr * 64 + mt * 16 + 4 * g + r] =
            (_Float16)(acc[mt][nt][r] + bb[r]);
    }
  }
  __syncthreads();

  // store: qkv[(qi*nb+bl)*4+head][w][h*64+d], h = tt (v6-proven pattern)
  const int qi = ft >> 1, head01 = (ft & 1) * 2;
  const int w = tid >> 1, dh = (tid & 1) * 32;
#pragma unroll
  for (int hh = 0; hh < 2; ++hh) {
    const int head = head01 + hh;
    const _Float16* s = sO + w * 132 + hh * 64 + dh;
    _Float16* dst =
        qkv + (((long)(qi * nb + bl) * 4 + head) * 128 + w) * 8192 + tt * 64 + dh;
#pragma unroll
    for (int e = 0; e < 8; ++e)
      *(u2*)(dst + e * 4) = *(const u2*)(s + e * 4);
  }
}

// ---------------- K2: attention per (w, head, bl) ---------------- (v7-proven)
__global__ __launch_bounds__(256) void k2_attn(const _Float16* __restrict__ qkv,
                                               _Float16* __restrict__ attnout,
                                               int nb) {
  const int w = blockIdx.x, head = blockIdx.y, bl = blockIdx.z;
  const int tid = threadIdx.x;
  const int lane = tid & 63, wv = tid >> 6;
  const int g = lane >> 4, l16 = lane & 15;

  __shared__ __align__(16) char smem[(128 * 72 * 2 + 64 * 136) * 2];  // 54272 B
  _Float16* sQ = (_Float16*)smem;
  _Float16* sK = sQ + 128 * 72;
  _Float16* sVT = sK + 128 * 72;
  _Float16* sP = sQ;
  _Float16* sO = sQ;

  const long base = (((long)bl * 4 + head) * 128 + w) * 8192;
  const long QS = (long)nb * 4 * 128 * 8192;
  const _Float16* qg = qkv + base;
  const _Float16* kg = qkv + base + QS;
  const _Float16* vg = qkv + base + 2 * QS;

#pragma unroll
  for (int i = 0; i < 4; ++i) {
    int u = tid + 256 * i;
    int hh = u >> 3, dq = u & 7;
    *(u4*)(sQ + hh * 72 + dq * 8) = *(const u4*)(qg + hh * 64 + dq * 8);
    *(u4*)(sK + hh * 72 + dq * 8) = *(const u4*)(kg + hh * 64 + dq * 8);
  }
  {
    const int hh = tid & 127, dc = tid >> 7;
#pragma unroll
    for (int jj = 0; jj < 4; ++jj) {
      u4 vv = *(const u4*)(vg + hh * 64 + dc * 32 + jj * 8);
      const _Float16* pe = (const _Float16*)&vv;
#pragma unroll
      for (int e = 0; e < 8; ++e)
        sVT[(dc * 32 + jj * 8 + e) * 136 + hh] = pe[e];
    }
  }
  __syncthreads();

  f4 accS[8][2];
  for (int i = 0; i < 8; ++i)
    for (int jt = 0; jt < 2; ++jt)
      for (int r = 0; r < 4; ++r) accS[i][jt][r] = 0.f;
#pragma unroll
  for (int ks = 0; ks < 2; ++ks) {
    const int k = ks * 32 + 8 * g;
    h8 af[8], bf[2];
#pragma unroll
    for (int i = 0; i < 8; ++i)
      af[i] = *(const h8*)(sK + (i * 16 + l16) * 72 + k);
#pragma unroll
    for (int jt = 0; jt < 2; ++jt)
      bf[jt] = *(const h8*)(sQ + (wv * 32 + jt * 16 + l16) * 72 + k);
#pragma unroll
    for (int i = 0; i < 8; ++i)
#pragma unroll
      for (int jt = 0; jt < 2; ++jt)
        accS[i][jt] = MFMA32(af[i], bf[jt], accS[i][jt]);
  }

  float rinv[2];
#pragma unroll
  for (int jt = 0; jt < 2; ++jt) {
    float m = -1e30f;
    for (int i = 0; i < 8; ++i)
      for (int r = 0; r < 4; ++r) m = fmaxf(m, accS[i][jt][r]);
    m = fmaxf(m, __shfl_xor(m, 16));
    m = fmaxf(m, __shfl_xor(m, 32));
    float s = 0.f;
    for (int i = 0; i < 8; ++i)
      for (int r = 0; r < 4; ++r) {
        float p = __expf((accS[i][jt][r] - m) * 0.125f);
        accS[i][jt][r] = p;
        s += p;
      }
    s += __shfl_xor(s, 16);
    s += __shfl_xor(s, 32);
    rinv[jt] = 1.0f / s;
  }

  __syncthreads();
#pragma unroll
  for (int jt = 0; jt < 2; ++jt) {
    const int hq = wv * 32 + jt * 16 + l16;
#pragma unroll
    for (int i = 0; i < 8; ++i) {
      h4 pv;
      pv[0] = (_Float16)accS[i][jt][0];
      pv[1] = (_Float16)accS[i][jt][1];
      pv[2] = (_Float16)accS[i][jt][2];
      pv[3] = (_Float16)accS[i][jt][3];
      *(h4*)(sP + hq * 136 + i * 16 + 4 * g) = pv;
    }
  }
  __syncthreads();

  f4 accO[4][2];
  for (int mt = 0; mt < 4; ++mt)
    for (int jt = 0; jt < 2; ++jt)
      for (int r = 0; r < 4; ++r) accO[mt][jt][r] = 0.f;
#pragma unroll
  for (int i2 = 0; i2 < 4; ++i2) {
    const int k = i2 * 32 + 8 * g;
    h8 av[4], pb[2];
#pragma unroll
    for (int mt = 0; mt < 4; ++mt)
      av[mt] = *(const h8*)(sVT + (mt * 16 + l16) * 136 + k);
#pragma unroll
    for (int jt = 0; jt < 2; ++jt)
      pb[jt] = *(const h8*)(sP + (wv * 32 + jt * 16 + l16) * 136 + k);
#pragma unroll
    for (int mt = 0; mt < 4; ++mt)
#pragma unroll
      for (int jt = 0; jt < 2; ++jt)
        accO[mt][jt] = MFMA32(av[mt], pb[jt], accO[mt][jt]);
  }

  __syncthreads();
#pragma unroll
  for (int mt = 0; mt < 4; ++mt)
#pragma unroll
    for (int jt = 0; jt < 2; ++jt)
#pragma unroll
      for (int r = 0; r < 4; ++r)
        sO[(wv * 32 + jt * 16 + l16) * 72 + mt * 16 + 4 * g + r] =
            (_Float16)(accO[mt][jt][r] * rinv[jt]);
  __syncthreads();

  const int hh = tid >> 1, d0 = (tid & 1) * 32;
  const _Float16* s = sO + hh * 72 + d0;
  _Float16* dst = attnout + ((long)bl * 16384 + hh * 128 + w) * 256 + head * 64 + d0;
#pragma unroll
  for (int e = 0; e < 4; ++e)
    *(u4*)(dst + e * 8) = *(const u4*)(s + e * 8);
}

// ---------------- K3: out[b][co][t] = Wproj^T[co][c]*attnout[t][c]+bproj --------
// grid (ct=2, tt=128, bl). Tile 128co x 128t, BK=64, 2x2 waves, gload_lds staging.
__global__ __launch_bounds__(256, 4) void k3_proj(const _Float16* __restrict__ attnout,
                                                  const _Float16* __restrict__ wpt,
                                                  const float* __restrict__ bproj,
                                                  float* __restrict__ out,
                                                  int b_base, int nb) {
  const int ct = blockIdx.x, tt = blockIdx.y, bl = blockIdx.z;
  const int b = b_base + bl;
  const int tid = threadIdx.x;
  const int lane = tid & 63, wv = tid >> 6;
  const int g = lane >> 4, l16 = lane & 15;
  const int wr = wv >> 1, wc = wv & 1;
  const int co0 = ct * 128;
  const long t0 = (long)tt * 128;

  __shared__ __align__(16) char smem[33792];
  _Float16* sA = (_Float16*)smem;   // [128 co][64]
  _Float16* sB = sA + 128 * 64;     // [128 t][64]
  float* sOut = (float*)smem;       // reuse: [64][132] f32

  f4 acc[4][4];
#pragma unroll
  for (int mt = 0; mt < 4; ++mt)
#pragma unroll
    for (int nt = 0; nt < 4; ++nt)
#pragma unroll
      for (int r = 0; r < 4; ++r) acc[mt][nt][r] = 0.f;

  const _Float16* Ab = wpt + (long)co0 * 256;
  const _Float16* Bb = attnout + ((long)bl * 16384 + t0) * 256;
  const int r0 = wv * 32;
  const int rl = lane >> 3, ch = (lane & 7) * 8;

  for (int kc = 0; kc < 4; ++kc) {
    const int c0 = kc * 64;
#pragma unroll
    for (int i = 0; i < 4; ++i) {
      const int row = r0 + i * 8 + rl;
      gll16(Ab + (long)row * 256 + c0 + ch, sA + (r0 + i * 8) * 64);
      gll16(Bb + (long)row * 256 + c0 + ch, sB + (r0 + i * 8) * 64);
    }
    __syncthreads();
#pragma unroll
    for (int ks = 0; ks < 2; ++ks) {
      const int k = ks * 32 + 8 * g;
      h8 af[4], bf[4];
#pragma unroll
      for (int mt = 0; mt < 4; ++mt)
        af[mt] = *(const h8*)(sA + (wr * 64 + mt * 16 + l16) * 64 + k);
#pragma unroll
      for (int nt = 0; nt < 4; ++nt)
        bf[nt] = *(const h8*)(sB + (wc * 64 + nt * 16 + l16) * 64 + k);
#pragma unroll
      for (int mt = 0; mt < 4; ++mt)
#pragma unroll
        for (int nt = 0; nt < 4; ++nt)
          acc[mt][nt] = MFMA32(af[mt], bf[nt], acc[mt][nt]);
    }
    __syncthreads();
  }

  // epilogue: two co-halves; wave-half wr==h2 repacks, all threads store f4 rows
#pragma unroll
  for (int h2 = 0; h2 < 2; ++h2) {
    if (h2) __syncthreads();
    if (wr == h2) {
#pragma unroll
      for (int mt = 0; mt < 4; ++mt) {
        f4 bb = *(const f4*)(bproj + co0 + h2 * 64 + mt * 16 + 4 * g);
#pragma unroll
        for (int nt = 0; nt < 4; ++nt)
#pragma unroll
          for (int r = 0; r < 4; ++r)
            sOut[(mt * 16 + 4 * g + r) * 132 + wc * 64 + nt * 16 + l16] =
                acc[mt][nt][r] + bb[r];
      }
    }
    __syncthreads();
    const int row = tid >> 2, seg = (tid & 3) * 32;
    const float* s = sOut + row * 132 + seg;
    float* dst = out + ((long)b * 256 + co0 + h2 * 64 + row) * 16384 + t0 + seg;
#pragma unroll
    for (int e = 0; e < 8; ++e)
      *(f4*)(dst + e * 4) = *(const f4*)(s + e * 4);
  }
}

// ---------------- launch ----------------
extern "C" void kernel_launch(void* const* d_in, const int* in_sizes, int n_in,
                              void* d_out, int out_size, void* d_ws, size_t ws_size,
                              hipStream_t stream) {
  const float* x = (const float*)d_in[0];
  const float* Wqkv = (const float*)d_in[1];
  const float* bqkv = (const float*)d_in[2];
  const float* Wproj = (const float*)d_in[3];
  const float* bproj = (const float*)d_in[4];
  float* out = (float*)d_out;

  char* ws = (char*)d_ws;
  // Layout: [wqt 384K][wpt 128K][qkv nb*24Mi][shared nb*8Mi (xt, then attnout)]
  const long WQT = 393216L, WPT = 131072L;
  const long PER_B = 25165824L + 8388608L;
  long nb_l = ((long)ws_size - (WQT + WPT)) / PER_B;
  int nb = nb_l < 1 ? 1 : (nb_l > 8 ? 8 : (int)nb_l);

  _Float16* wqt = (_Float16*)ws;
  _Float16* wpt = (_Float16*)(ws + WQT);
  _Float16* qkv = (_Float16*)(ws + WQT + WPT);
  _Float16* shared = (_Float16*)(ws + WQT + WPT + (long)nb * 25165824L);
  _Float16* xt = shared;       // live: prep_x -> k1
  _Float16* attnout = shared;  // live: k2 -> k3 (after xt dead)

  prep_w<<<1024, 256, 0, stream>>>(Wqkv, Wproj, wqt, wpt);

  for (int b0 = 0; b0 < 8; b0 += nb) {
    int nbv = (8 - b0 < nb) ? (8 - b0) : nb;
    prep_x<<<dim3(128, nbv), 256, 0, stream>>>(x, xt, b0);
    k1_qkv<<<768 * nbv, 256, 0, stream>>>(xt, wqt, bqkv, qkv, nbv);
    k2_attn<<<dim3(128, 4, nbv), 256, 0, stream>>>(qkv, attnout, nbv);
    k3_proj<<<dim3(2, 128, nbv), 256, 0, stream>>>(attnout, wpt, bproj, out, b0, nbv);
  }
}

// Round 9
// 254.904 us; speedup vs baseline: 1.3821x; 1.0467x over previous
//
#include <hip/hip_runtime.h>

// AxisAttention: x(8,256,128,128) -> per (b,w) sequence over h: QKV GEMM, 4-head
// attention (S=128, d=64), proj GEMM, transposed fp32 output.
// All matmuls: v_mfma_f32_16x16x32_f16, fp32 accum.
// v9: token enumeration t' = w*128+h (h fastest). k1's per-(qi,head) f-half for a
//     t'-tile (fixed w) is a contiguous 16KB qkv chunk -> fully coalesced u4
//     epilogue (v8's 8B-granule scatter was the hidden k1 cost). prep_x phase-2
//     now does 8x8 register-tile transpose (vector LDS reads, coalesced stores).
//     qkv layout + k2 + k3 unchanged from v8.

typedef _Float16 h4 __attribute__((ext_vector_type(4)));
typedef _Float16 h8 __attribute__((ext_vector_type(8)));
typedef float f4 __attribute__((ext_vector_type(4)));
typedef unsigned int u4 __attribute__((ext_vector_type(4)));

#define MFMA32(a, b, c) __builtin_amdgcn_mfma_f32_16x16x32_f16((a), (b), (c), 0, 0, 0)

__device__ __forceinline__ void gll16(const _Float16* g, _Float16* l) {
  __builtin_amdgcn_global_load_lds(
      (const __attribute__((address_space(1))) void*)g,
      (__attribute__((address_space(3))) void*)l, 16, 0, 0);
}

// ---------------- prep: W^T fp16 (wqt[f][c], wpt[f][c]) ----------------
__global__ __launch_bounds__(256) void prep_w(const float* __restrict__ Wqkv,
                                              const float* __restrict__ Wproj,
                                              _Float16* __restrict__ wqt,
                                              _Float16* __restrict__ wpt) {
  int i = blockIdx.x * 256 + threadIdx.x;  // 196608 + 65536
  if (i < 768 * 256) {
    int f = i >> 8, c = i & 255;
    wqt[i] = (_Float16)Wqkv[c * 768 + f];
  } else {
    int j = i - 768 * 256;
    int f = j >> 8, c = j & 255;
    wpt[j] = (_Float16)Wproj[c * 256 + f];
  }
}

// ---------------- prep_x: x[b][c][h][w] fp32 -> xt[bl][w*128+h][c] fp16 --------
// grid (h=128, bl), block 256. Phase1: coalesced f4 reads -> LDS [c][w].
// Phase2: 8x8 register-tile transpose; stores 16B-granule, 512B-contiguous runs.
__global__ __launch_bounds__(256) void prep_x(const float* __restrict__ x,
                                              _Float16* __restrict__ xt,
                                              int b_base) {
  const int h = blockIdx.x, bl = blockIdx.y;
  const int b = b_base + bl;
  const int tid = threadIdx.x;
  __shared__ __align__(16) _Float16 sT[256 * 132];  // 67584 B, pitch 132

  // phase 1: lane wj covers w-chunk, cg covers c-group
  const int wj = tid & 31, cg = tid >> 5;
#pragma unroll
  for (int ci = 0; ci < 32; ++ci) {
    const int c = cg * 32 + ci;
    f4 v = *(const f4*)(x + (((long)b * 256 + c) * 128 + h) * 128 + wj * 4);
    h4 o;
    o[0] = (_Float16)v[0]; o[1] = (_Float16)v[1];
    o[2] = (_Float16)v[2]; o[3] = (_Float16)v[3];
    *(h4*)(sT + c * 132 + wj * 4) = o;
  }
  __syncthreads();

  // phase 2: 512 8x8 tiles (cb 0..31, wb 0..15); thread t handles t and t+256
#pragma unroll
  for (int tt2 = tid; tt2 < 512; tt2 += 256) {
    const int cb = tt2 & 31, wb = tt2 >> 5;
    h8 r[8];
#pragma unroll
    for (int j = 0; j < 8; ++j)
      r[j] = *(const h8*)(sT + (cb * 8 + j) * 132 + wb * 8);
#pragma unroll
    for (int i = 0; i < 8; ++i) {
      h8 o;
#pragma unroll
      for (int j = 0; j < 8; ++j) o[j] = r[j][i];
      const int w = wb * 8 + i;
      *(h8*)(xt + ((long)bl * 16384 + w * 128 + h) * 256 + cb * 8) = o;
    }
  }
}

// ---------------- K1: qkv[f][t'] = Wqkv^T[f][c] * xt[t'][c] + bqkv --------------
// 1D grid 768*nbv XCD-swizzled. Tile 128f x 128t' (t' tile = one w, all h).
// BK=64, 4 waves (2f x 2t), global_load_lds staging, coalesced 16KB epilogue.
// qkv layout: [qi*nb+bl][head][w][h*64+d]  (identical to v8; k2 unchanged)
__global__ __launch_bounds__(256, 4) void k1_qkv(const _Float16* __restrict__ xt,
                                                 const _Float16* __restrict__ wqt,
                                                 const float* __restrict__ bqkv,
                                                 _Float16* __restrict__ qkv,
                                                 int nb) {
  const int wg = blockIdx.x;
  const int xcd = wg & 7, gseq = wg >> 3;
  const int ft = gseq % 6, ghi = gseq / 6;
  const int G = ghi * 8 + xcd;          // [0, 128*nbv)
  const int tt = G & 127, bl = G >> 7;  // tile: w = tt, h = 0..127

  const int tid = threadIdx.x;
  const int lane = tid & 63, wv = tid >> 6;
  const int g = lane >> 4, l16 = lane & 15;
  const int wr = wv >> 1, wc = wv & 1;
  const int f0 = ft * 128;

  __shared__ __align__(16) char smem[34816];
  _Float16* sA = (_Float16*)smem;   // [128 f][64]
  _Float16* sB = sA + 128 * 64;     // [128 t'][64]
  _Float16* sO = sA;                // reuse: [128 t'][136]

  f4 acc[4][4];
#pragma unroll
  for (int mt = 0; mt < 4; ++mt)
#pragma unroll
    for (int nt = 0; nt < 4; ++nt)
#pragma unroll
      for (int r = 0; r < 4; ++r) acc[mt][nt][r] = 0.f;

  const _Float16* Ab = wqt + (long)f0 * 256;
  const _Float16* Bb = xt + ((long)bl * 16384 + tt * 128) * 256;
  const int r0 = wv * 32;
  const int rl = lane >> 3, ch = (lane & 7) * 8;

  for (int kc = 0; kc < 4; ++kc) {
    const int c0 = kc * 64;
#pragma unroll
    for (int i = 0; i < 4; ++i) {
      const int row = r0 + i * 8 + rl;
      gll16(Ab + (long)row * 256 + c0 + ch, sA + (r0 + i * 8) * 64);
      gll16(Bb + (long)row * 256 + c0 + ch, sB + (r0 + i * 8) * 64);
    }
    __syncthreads();
#pragma unroll
    for (int ks = 0; ks < 2; ++ks) {
      const int k = ks * 32 + 8 * g;
      h8 af[4], bf[4];
#pragma unroll
      for (int mt = 0; mt < 4; ++mt)
        af[mt] = *(const h8*)(sA + (wr * 64 + mt * 16 + l16) * 64 + k);
#pragma unroll
      for (int nt = 0; nt < 4; ++nt)
        bf[nt] = *(const h8*)(sB + (wc * 64 + nt * 16 + l16) * 64 + k);
#pragma unroll
      for (int mt = 0; mt < 4; ++mt)
#pragma unroll
        for (int nt = 0; nt < 4; ++nt)
          acc[mt][nt] = MFMA32(af[mt], bf[nt], acc[mt][nt]);
    }
    __syncthreads();
  }

  // bias + repack: sO[t'_local][f_local 0..127], pitch 136 (16B-aligned rows)
#pragma unroll
  for (int mt = 0; mt < 4; ++mt) {
    f4 bb = *(const f4*)(bqkv + f0 + wr * 64 + mt * 16 + 4 * g);
#pragma unroll
    for (int nt = 0; nt < 4; ++nt) {
      const int tl = wc * 64 + nt * 16 + l16;
#pragma unroll
      for (int r = 0; r < 4; ++r)
        sO[tl * 136 + wr * 64 + mt * 16 + 4 * g + r] =
            (_Float16)(acc[mt][nt][r] + bb[r]);
    }
  }
  __syncthreads();

  // store: per f-half -> one (qi,head): 16KB contiguous at qkv[...][w=tt][h][d]
  const int hh = tid >> 1, dh = (tid & 1) * 32;
#pragma unroll
  for (int h2 = 0; h2 < 2; ++h2) {
    const int fh = f0 + h2 * 64;
    const int qi = fh >> 8, head = (fh >> 6) & 3;
    _Float16* dst =
        qkv + (((long)(qi * nb + bl) * 4 + head) * 128 + tt) * 8192 + hh * 64 + dh;
    const _Float16* s = sO + hh * 136 + h2 * 64 + dh;
#pragma unroll
    for (int e = 0; e < 4; ++e)
      *(u4*)(dst + e * 8) = *(const u4*)(s + e * 8);
  }
}

// ---------------- K2: attention per (w, head, bl) ---------------- (unchanged)
__global__ __launch_bounds__(256) void k2_attn(const _Float16* __restrict__ qkv,
                                               _Float16* __restrict__ attnout,
                                               int nb) {
  const int w = blockIdx.x, head = blockIdx.y, bl = blockIdx.z;
  const int tid = threadIdx.x;
  const int lane = tid & 63, wv = tid >> 6;
  const int g = lane >> 4, l16 = lane & 15;

  __shared__ __align__(16) char smem[(128 * 72 * 2 + 64 * 136) * 2];  // 54272 B
  _Float16* sQ = (_Float16*)smem;
  _Float16* sK = sQ + 128 * 72;
  _Float16* sVT = sK + 128 * 72;
  _Float16* sP = sQ;
  _Float16* sO = sQ;

  const long base = (((long)bl * 4 + head) * 128 + w) * 8192;
  const long QS = (long)nb * 4 * 128 * 8192;
  const _Float16* qg = qkv + base;
  const _Float16* kg = qkv + base + QS;
  const _Float16* vg = qkv + base + 2 * QS;

#pragma unroll
  for (int i = 0; i < 4; ++i) {
    int u = tid + 256 * i;
    int hh = u >> 3, dq = u & 7;
    *(u4*)(sQ + hh * 72 + dq * 8) = *(const u4*)(qg + hh * 64 + dq * 8);
    *(u4*)(sK + hh * 72 + dq * 8) = *(const u4*)(kg + hh * 64 + dq * 8);
  }
  {
    const int hh = tid & 127, dc = tid >> 7;
#pragma unroll
    for (int jj = 0; jj < 4; ++jj) {
      u4 vv = *(const u4*)(vg + hh * 64 + dc * 32 + jj * 8);
      const _Float16* pe = (const _Float16*)&vv;
#pragma unroll
      for (int e = 0; e < 8; ++e)
        sVT[(dc * 32 + jj * 8 + e) * 136 + hh] = pe[e];
    }
  }
  __syncthreads();

  f4 accS[8][2];
  for (int i = 0; i < 8; ++i)
    for (int jt = 0; jt < 2; ++jt)
      for (int r = 0; r < 4; ++r) accS[i][jt][r] = 0.f;
#pragma unroll
  for (int ks = 0; ks < 2; ++ks) {
    const int k = ks * 32 + 8 * g;
    h8 af[8], bf[2];
#pragma unroll
    for (int i = 0; i < 8; ++i)
      af[i] = *(const h8*)(sK + (i * 16 + l16) * 72 + k);
#pragma unroll
    for (int jt = 0; jt < 2; ++jt)
      bf[jt] = *(const h8*)(sQ + (wv * 32 + jt * 16 + l16) * 72 + k);
#pragma unroll
    for (int i = 0; i < 8; ++i)
#pragma unroll
      for (int jt = 0; jt < 2; ++jt)
        accS[i][jt] = MFMA32(af[i], bf[jt], accS[i][jt]);
  }

  float rinv[2];
#pragma unroll
  for (int jt = 0; jt < 2; ++jt) {
    float m = -1e30f;
    for (int i = 0; i < 8; ++i)
      for (int r = 0; r < 4; ++r) m = fmaxf(m, accS[i][jt][r]);
    m = fmaxf(m, __shfl_xor(m, 16));
    m = fmaxf(m, __shfl_xor(m, 32));
    float s = 0.f;
    for (int i = 0; i < 8; ++i)
      for (int r = 0; r < 4; ++r) {
        float p = __expf((accS[i][jt][r] - m) * 0.125f);
        accS[i][jt][r] = p;
        s += p;
      }
    s += __shfl_xor(s, 16);
    s += __shfl_xor(s, 32);
    rinv[jt] = 1.0f / s;
  }

  __syncthreads();
#pragma unroll
  for (int jt = 0; jt < 2; ++jt) {
    const int hq = wv * 32 + jt * 16 + l16;
#pragma unroll
    for (int i = 0; i < 8; ++i) {
      h4 pv;
      pv[0] = (_Float16)accS[i][jt][0];
      pv[1] = (_Float16)accS[i][jt][1];
      pv[2] = (_Float16)accS[i][jt][2];
      pv[3] = (_Float16)accS[i][jt][3];
      *(h4*)(sP + hq * 136 + i * 16 + 4 * g) = pv;
    }
  }
  __syncthreads();

  f4 accO[4][2];
  for (int mt = 0; mt < 4; ++mt)
    for (int jt = 0; jt < 2; ++jt)
      for (int r = 0; r < 4; ++r) accO[mt][jt][r] = 0.f;
#pragma unroll
  for (int i2 = 0; i2 < 4; ++i2) {
    const int k = i2 * 32 + 8 * g;
    h8 av[4], pb[2];
#pragma unroll
    for (int mt = 0; mt < 4; ++mt)
      av[mt] = *(const h8*)(sVT + (mt * 16 + l16) * 136 + k);
#pragma unroll
    for (int jt = 0; jt < 2; ++jt)
      pb[jt] = *(const h8*)(sP + (wv * 32 + jt * 16 + l16) * 136 + k);
#pragma unroll
    for (int mt = 0; mt < 4; ++mt)
#pragma unroll
      for (int jt = 0; jt < 2; ++jt)
        accO[mt][jt] = MFMA32(av[mt], pb[jt], accO[mt][jt]);
  }

  __syncthreads();
#pragma unroll
  for (int mt = 0; mt < 4; ++mt)
#pragma unroll
    for (int jt = 0; jt < 2; ++jt)
#pragma unroll
      for (int r = 0; r < 4; ++r)
        sO[(wv * 32 + jt * 16 + l16) * 72 + mt * 16 + 4 * g + r] =
            (_Float16)(accO[mt][jt][r] * rinv[jt]);
  __syncthreads();

  const int hh = tid >> 1, d0 = (tid & 1) * 32;
  const _Float16* s = sO + hh * 72 + d0;
  _Float16* dst = attnout + ((long)bl * 16384 + hh * 128 + w) * 256 + head * 64 + d0;
#pragma unroll
  for (int e = 0; e < 4; ++e)
    *(u4*)(dst + e * 8) = *(const u4*)(s + e * 8);
}

// ---------------- K3: out[b][co][t] = Wproj^T[co][c]*attnout[t][c]+bproj --------
// (unchanged from v8)
__global__ __launch_bounds__(256, 4) void k3_proj(const _Float16* __restrict__ attnout,
                                                  const _Float16* __restrict__ wpt,
                                                  const float* __restrict__ bproj,
                                                  float* __restrict__ out,
                                                  int b_base, int nb) {
  const int ct = blockIdx.x, tt = blockIdx.y, bl = blockIdx.z;
  const int b = b_base + bl;
  const int tid = threadIdx.x;
  const int lane = tid & 63, wv = tid >> 6;
  const int g = lane >> 4, l16 = lane & 15;
  const int wr = wv >> 1, wc = wv & 1;
  const int co0 = ct * 128;
  const long t0 = (long)tt * 128;

  __shared__ __align__(16) char smem[33792];
  _Float16* sA = (_Float16*)smem;   // [128 co][64]
  _Float16* sB = sA + 128 * 64;     // [128 t][64]
  float* sOut = (float*)smem;       // reuse: [64][132] f32

  f4 acc[4][4];
#pragma unroll
  for (int mt = 0; mt < 4; ++mt)
#pragma unroll
    for (int nt = 0; nt < 4; ++nt)
#pragma unroll
      for (int r = 0; r < 4; ++r) acc[mt][nt][r] = 0.f;

  const _Float16* Ab = wpt + (long)co0 * 256;
  const _Float16* Bb = attnout + ((long)bl * 16384 + t0) * 256;
  const int r0 = wv * 32;
  const int rl = lane >> 3, ch = (lane & 7) * 8;

  for (int kc = 0; kc < 4; ++kc) {
    const int c0 = kc * 64;
#pragma unroll
    for (int i = 0; i < 4; ++i) {
      const int row = r0 + i * 8 + rl;
      gll16(Ab + (long)row * 256 + c0 + ch, sA + (r0 + i * 8) * 64);
      gll16(Bb + (long)row * 256 + c0 + ch, sB + (r0 + i * 8) * 64);
    }
    __syncthreads();
#pragma unroll
    for (int ks = 0; ks < 2; ++ks) {
      const int k = ks * 32 + 8 * g;
      h8 af[4], bf[4];
#pragma unroll
      for (int mt = 0; mt < 4; ++mt)
        af[mt] = *(const h8*)(sA + (wr * 64 + mt * 16 + l16) * 64 + k);
#pragma unroll
      for (int nt = 0; nt < 4; ++nt)
        bf[nt] = *(const h8*)(sB + (wc * 64 + nt * 16 + l16) * 64 + k);
#pragma unroll
      for (int mt = 0; mt < 4; ++mt)
#pragma unroll
        for (int nt = 0; nt < 4; ++nt)
          acc[mt][nt] = MFMA32(af[mt], bf[nt], acc[mt][nt]);
    }
    __syncthreads();
  }

#pragma unroll
  for (int h2 = 0; h2 < 2; ++h2) {
    if (h2) __syncthreads();
    if (wr == h2) {
#pragma unroll
      for (int mt = 0; mt < 4; ++mt) {
        f4 bb = *(const f4*)(bproj + co0 + h2 * 64 + mt * 16 + 4 * g);
#pragma unroll
        for (int nt = 0; nt < 4; ++nt)
#pragma unroll
          for (int r = 0; r < 4; ++r)
            sOut[(mt * 16 + 4 * g + r) * 132 + wc * 64 + nt * 16 + l16] =
                acc[mt][nt][r] + bb[r];
      }
    }
    __syncthreads();
    const int row = tid >> 2, seg = (tid & 3) * 32;
    const float* s = sOut + row * 132 + seg;
    float* dst = out + ((long)b * 256 + co0 + h2 * 64 + row) * 16384 + t0 + seg;
#pragma unroll
    for (int e = 0; e < 8; ++e)
      *(f4*)(dst + e * 4) = *(const f4*)(s + e * 4);
  }
}

// ---------------- launch ----------------
extern "C" void kernel_launch(void* const* d_in, const int* in_sizes, int n_in,
                              void* d_out, int out_size, void* d_ws, size_t ws_size,
                              hipStream_t stream) {
  const float* x = (const float*)d_in[0];
  const float* Wqkv = (const float*)d_in[1];
  const float* bqkv = (const float*)d_in[2];
  const float* Wproj = (const float*)d_in[3];
  const float* bproj = (const float*)d_in[4];
  float* out = (float*)d_out;

  char* ws = (char*)d_ws;
  // Layout: [wqt 384K][wpt 128K][qkv nb*24Mi][shared nb*8Mi (xt, then attnout)]
  const long WQT = 393216L, WPT = 131072L;
  const long PER_B = 25165824L + 8388608L;
  long nb_l = ((long)ws_size - (WQT + WPT)) / PER_B;
  int nb = nb_l < 1 ? 1 : (nb_l > 8 ? 8 : (int)nb_l);

  _Float16* wqt = (_Float16*)ws;
  _Float16* wpt = (_Float16*)(ws + WQT);
  _Float16* qkv = (_Float16*)(ws + WQT + WPT);
  _Float16* shared = (_Float16*)(ws + WQT + WPT + (long)nb * 25165824L);
  _Float16* xt = shared;       // live: prep_x -> k1
  _Float16* attnout = shared;  // live: k2 -> k3 (after xt dead)

  prep_w<<<1024, 256, 0, stream>>>(Wqkv, Wproj, wqt, wpt);

  for (int b0 = 0; b0 < 8; b0 += nb) {
    int nbv = (8 - b0 < nb) ? (8 - b0) : nb;
    prep_x<<<dim3(128, nbv), 256, 0, stream>>>(x, xt, b0);
    k1_qkv<<<768 * nbv, 256, 0, stream>>>(xt, wqt, bqkv, qkv, nbv);
    k2_attn<<<dim3(128, 4, nbv), 256, 0, stream>>>(qkv, attnout, nbv);
    k3_proj<<<dim3(2, 128, nbv), 256, 0, stream>>>(attnout, wpt, bproj, out, b0, nbv);
  }
}